// Round 1
// baseline (14694.481 us; speedup 1.0000x reference)
//
#include <hip/hip_runtime.h>
#include <cstdio>

#define N_NODES 15000
#define N_E     200000
#define N_EA    400000
#define N_R     1000
#define N_B     512
#define D_EH    300
#define D_X     900

__device__ __forceinline__ float lrelu_f(float x){ return x > 0.f ? x : 0.01f*x; }
__device__ __forceinline__ float sigm_f(float x){ return 1.f/(1.f+expf(-x)); }

// ---------------- CSR build ----------------
__global__ void k_count(const int* __restrict__ tgt, int n, int* __restrict__ cnt){
    int i = blockIdx.x*blockDim.x + threadIdx.x;
    if (i < n) atomicAdd(&cnt[tgt[i]], 1);
}

__global__ __launch_bounds__(1024) void k_scan(const int* __restrict__ cnt, int* __restrict__ ptr, int n){
    __shared__ int part[1024];
    int tid = threadIdx.x;
    int chunk = (n + 1023) >> 10;
    int beg = tid*chunk, end = min(n, beg+chunk);
    int s = 0;
    for (int i = beg; i < end; ++i) s += cnt[i];
    part[tid] = s;
    __syncthreads();
    if (tid == 0){
        int run = 0;
        for (int i = 0; i < 1024; ++i){ int v = part[i]; part[i] = run; run += v; }
        ptr[n] = run;
    }
    __syncthreads();
    int run = part[tid];
    for (int i = beg; i < end; ++i){ ptr[i] = run; run += cnt[i]; }
}

__global__ void k_fill_node_csr(const int* __restrict__ ei, int n, const int* __restrict__ ptr,
                                int* __restrict__ cur, int* __restrict__ col){
    int e = blockIdx.x*blockDim.x + threadIdx.x;
    if (e < n){
        int j = ei[e], i = ei[n + e];
        int p = atomicAdd(&cur[i], 1);
        col[ptr[i] + p] = j;
    }
}

__global__ void k_fill_rel_csr(const int* __restrict__ rel, int n, const int* __restrict__ ptr,
                               int* __restrict__ cur, int* __restrict__ out){
    int e = blockIdx.x*blockDim.x + threadIdx.x;
    if (e < n){
        int r = rel[e];
        int p = atomicAdd(&cur[r], 1);
        out[ptr[r] + p] = e;
    }
}

__global__ void k_dis(const int* __restrict__ cnt, float* __restrict__ dis, int n){
    int i = blockIdx.x*blockDim.x + threadIdx.x;
    if (i < n){ int d = cnt[i]; dis[i] = d > 0 ? rsqrtf((float)d) : 0.f; }
}

// ---------------- GCN ----------------
__global__ __launch_bounds__(128) void k_gcn_agg(const float* __restrict__ x,
        const int* __restrict__ ptr, const int* __restrict__ col,
        const float* __restrict__ dis, float* __restrict__ out){
    int n = blockIdx.x, tid = threadIdx.x;
    int beg = ptr[n], end = ptr[n+1];
    float a0 = 0.f, a1 = 0.f, a2 = 0.f;
    for (int p = beg; p < end; ++p){
        int j = col[p];
        float dj = dis[j];
        const float* xr = x + (size_t)j*D_EH;
        a0 += dj * xr[tid];
        a1 += dj * xr[tid+128];
        if (tid < 44) a2 += dj * xr[tid+256];
    }
    float dn = dis[n];
    float* orow = out + (size_t)n*D_EH;
    orow[tid]     = fmaxf(dn*a0, 0.f);
    orow[tid+128] = fmaxf(dn*a1, 0.f);
    if (tid < 44) orow[tid+256] = fmaxf(dn*a2, 0.f);
}

__global__ void k_highway(float* __restrict__ x1, const float* __restrict__ x2,
                          const float* __restrict__ g, int n){
    int i = blockIdx.x*blockDim.x + threadIdx.x;
    if (i < n){
        float gg = g[i];
        x1[i] = lrelu_f(gg*x2[i] + (1.f-gg)*x1[i]);
    }
}

// ---------------- generic GEMMs (fp32, 64x64x16, 4x4/thread) ----------------
// C = act( [C +] A(M,K) @ B(N,K)^T + bias1 + bias2 )
__global__ __launch_bounds__(256)
void gemm_abt(const float* __restrict__ A, int lda,
              const float* __restrict__ B, int ldb,
              float* __restrict__ C, int ldc,
              int M, int N, int K,
              const float* __restrict__ bias1,
              const float* __restrict__ bias2,
              int accum, int act)
{
    __shared__ float As[16][65];
    __shared__ float Bs[16][65];
    const int bm = blockIdx.y*64, bn = blockIdx.x*64;
    const int tid = threadIdx.x;
    const int tx = tid & 15, ty = tid >> 4;
    const int ar = tid >> 2, ac = (tid & 3) << 2;
    float acc[4][4] = {{0.f}};
    for (int k0 = 0; k0 < K; k0 += 16){
        int am = bm + ar;
        const float* Arow = A + (size_t)am*lda;
        #pragma unroll
        for (int u = 0; u < 4; ++u){
            int kk = ac + u, k = k0 + kk;
            As[kk][ar] = (am < M && k < K) ? Arow[k] : 0.f;
        }
        int bnr = bn + ar;
        const float* Brow = B + (size_t)bnr*ldb;
        #pragma unroll
        for (int u = 0; u < 4; ++u){
            int kk = ac + u, k = k0 + kk;
            Bs[kk][ar] = (bnr < N && k < K) ? Brow[k] : 0.f;
        }
        __syncthreads();
        #pragma unroll
        for (int kk = 0; kk < 16; ++kk){
            float a[4], b[4];
            #pragma unroll
            for (int i = 0; i < 4; ++i) a[i] = As[kk][(ty<<2)+i];
            #pragma unroll
            for (int j = 0; j < 4; ++j) b[j] = Bs[kk][(tx<<2)+j];
            #pragma unroll
            for (int i = 0; i < 4; ++i)
                #pragma unroll
                for (int j = 0; j < 4; ++j)
                    acc[i][j] = fmaf(a[i], b[j], acc[i][j]);
        }
        __syncthreads();
    }
    #pragma unroll
    for (int i = 0; i < 4; ++i){
        int m = bm + (ty<<2) + i;
        if (m >= M) continue;
        float* Crow = C + (size_t)m*ldc;
        #pragma unroll
        for (int j = 0; j < 4; ++j){
            int n = bn + (tx<<2) + j;
            if (n >= N) continue;
            float v = acc[i][j];
            if (bias1) v += bias1[n];
            if (bias2) v += bias2[n];
            if (accum) v += Crow[n];
            if (act == 1) v = lrelu_f(v);
            else if (act == 2) v = fmaxf(v, 0.f);
            else if (act == 3) v = lrelu_f(v + 1e-8f);
            Crow[n] = v;
        }
    }
}

// C += A(M,K) @ B(K,N), split-K over grid.z chunks, atomicAdd epilogue
__global__ __launch_bounds__(256)
void gemm_ab_splitk(const float* __restrict__ A, int lda,
                    const float* __restrict__ B, int ldb,
                    float* __restrict__ C, int ldc,
                    int M, int N, int K, int kc)
{
    __shared__ float As[16][65];
    __shared__ float Bs[16][65];
    const int bm = blockIdx.y*64, bn = blockIdx.x*64;
    const int kbeg = blockIdx.z*kc;
    const int kend = min(K, kbeg + kc);
    const int tid = threadIdx.x;
    const int tx = tid & 15, ty = tid >> 4;
    const int ar = tid >> 2, ac = (tid & 3) << 2;
    const int br = tid >> 4, bc = (tid & 15) << 2;
    float acc[4][4] = {{0.f}};
    for (int k0 = kbeg; k0 < kend; k0 += 16){
        int am = bm + ar;
        const float* Arow = A + (size_t)am*lda;
        #pragma unroll
        for (int u = 0; u < 4; ++u){
            int kk = ac + u, k = k0 + kk;
            As[kk][ar] = (am < M && k < kend) ? Arow[k] : 0.f;
        }
        int kb = k0 + br;
        const float* Brow = B + (size_t)kb*ldb;
        #pragma unroll
        for (int u = 0; u < 4; ++u){
            int n = bn + bc + u;
            Bs[br][bc+u] = (kb < kend && n < N) ? Brow[n] : 0.f;
        }
        __syncthreads();
        #pragma unroll
        for (int kk = 0; kk < 16; ++kk){
            float a[4], b[4];
            #pragma unroll
            for (int i = 0; i < 4; ++i) a[i] = As[kk][(ty<<2)+i];
            #pragma unroll
            for (int j = 0; j < 4; ++j) b[j] = Bs[kk][(tx<<2)+j];
            #pragma unroll
            for (int i = 0; i < 4; ++i)
                #pragma unroll
                for (int j = 0; j < 4; ++j)
                    acc[i][j] = fmaf(a[i], b[j], acc[i][j]);
        }
        __syncthreads();
    }
    #pragma unroll
    for (int i = 0; i < 4; ++i){
        int m = bm + (ty<<2) + i;
        if (m >= M) continue;
        #pragma unroll
        for (int j = 0; j < 4; ++j){
            int n = bn + (tx<<2) + j;
            if (n >= N) continue;
            atomicAdd(&C[(size_t)m*ldc + n], acc[i][j]);
        }
    }
}

// ---------------- row dots / edge values ----------------
__global__ __launch_bounds__(256) void k_rowdot2(const float* __restrict__ X, int ldx, int D,
        const float* __restrict__ v1, const float* __restrict__ v2,
        float* __restrict__ o1, float* __restrict__ o2){
    __shared__ float s1s[256], s2s[256];
    int n = blockIdx.x, tid = threadIdx.x;
    const float* row = X + (size_t)n*ldx;
    float s1 = 0.f, s2 = 0.f;
    for (int d = tid; d < D; d += 256){
        float x = row[d];
        s1 += x*v1[d];
        if (v2) s2 += x*v2[d];
    }
    s1s[tid] = s1; s2s[tid] = s2;
    __syncthreads();
    for (int st = 128; st > 0; st >>= 1){
        if (tid < st){ s1s[tid] += s1s[tid+st]; s2s[tid] += s2s[tid+st]; }
        __syncthreads();
    }
    if (tid == 0){ o1[n] = s1s[0]; if (o2) o2[n] = s2s[0]; }
}

__global__ void k_edge_gate(const int* __restrict__ ei,
        const float* __restrict__ vh1, const float* __restrict__ vt1,
        const float* __restrict__ vh2, const float* __restrict__ vt2,
        float* __restrict__ e1l, float* __restrict__ e2l){
    int e = blockIdx.x*blockDim.x + threadIdx.x;
    if (e < N_E){
        int h = ei[e], t = ei[N_E + e];
        e1l[e] = lrelu_f(vh1[h] + vt1[t]);
        e2l[e] = lrelu_f(vh2[h] + vt2[t]);
    }
}

__global__ void k_edge_gatr(const int* __restrict__ ei, const int* __restrict__ rel,
        const float* __restrict__ ehd, const float* __restrict__ rdot,
        float* __restrict__ er){
    int e = blockIdx.x*blockDim.x + threadIdx.x;
    if (e < N_E){
        int h = ei[e];
        er[e] = lrelu_f(ehd[h] + rdot[rel[e]]);
    }
}

// ---------------- segment softmax stats ----------------
__global__ __launch_bounds__(256)
void k_seg_ms(const int* __restrict__ ptr, const int* __restrict__ lst,
              const float* __restrict__ v1, const float* __restrict__ v2,
              float* __restrict__ m1, float* __restrict__ s1,
              float* __restrict__ m2, float* __restrict__ s2)
{
    __shared__ float r1[256], r2[256];
    const int r = blockIdx.x, tid = threadIdx.x;
    const int beg = ptr[r], end = ptr[r+1];
    float mm1 = -3.4e38f, mm2 = -3.4e38f;
    for (int p = beg + tid; p < end; p += 256){
        int e = lst[p];
        mm1 = fmaxf(mm1, v1[e]);
        if (v2) mm2 = fmaxf(mm2, v2[e]);
    }
    r1[tid] = mm1; r2[tid] = mm2;
    __syncthreads();
    for (int st = 128; st > 0; st >>= 1){
        if (tid < st){ r1[tid] = fmaxf(r1[tid], r1[tid+st]); r2[tid] = fmaxf(r2[tid], r2[tid+st]); }
        __syncthreads();
    }
    float M1 = r1[0], M2 = r2[0];
    __syncthreads();
    float ss1 = 0.f, ss2 = 0.f;
    for (int p = beg + tid; p < end; p += 256){
        int e = lst[p];
        ss1 += expf(v1[e] - M1);
        if (v2) ss2 += expf(v2[e] - M2);
    }
    r1[tid] = ss1; r2[tid] = ss2;
    __syncthreads();
    for (int st = 128; st > 0; st >>= 1){
        if (tid < st){ r1[tid] += r1[tid+st]; r2[tid] += r2[tid+st]; }
        __syncthreads();
    }
    if (tid == 0){
        m1[r] = M1; s1[r] = r1[0];
        if (m2){ m2[r] = M2; s2[r] = r2[0]; }
    }
}

__global__ __launch_bounds__(64)
void k_seg_ms_node(const int* __restrict__ ptr, const int* __restrict__ col,
                   const float* __restrict__ di, const float* __restrict__ dj,
                   float* __restrict__ mN, float* __restrict__ sN)
{
    const int n = blockIdx.x, lane = threadIdx.x;
    const int beg = ptr[n], end = ptr[n+1];
    const float dn = di[n];
    float mm = -3.4e38f;
    for (int p = beg + lane; p < end; p += 64)
        mm = fmaxf(mm, lrelu_f(dn + dj[col[p]]));
    for (int off = 32; off > 0; off >>= 1)
        mm = fmaxf(mm, __shfl_xor(mm, off));
    float ss = 0.f;
    for (int p = beg + lane; p < end; p += 64)
        ss += expf(lrelu_f(dn + dj[col[p]]) - mm);
    for (int off = 32; off > 0; off >>= 1)
        ss += __shfl_xor(ss, off);
    if (lane == 0){ mN[n] = mm; sN[n] = ss; }
}

// ---------------- segment aggregations ----------------
__global__ __launch_bounds__(128)
void k_gate_agg(const int* __restrict__ ptr, const int* __restrict__ lst,
        const int* __restrict__ ei,
        const float* __restrict__ e1l, const float* __restrict__ m1, const float* __restrict__ s1,
        const float* __restrict__ e2l, const float* __restrict__ m2, const float* __restrict__ s2,
        const float* __restrict__ xh, const float* __restrict__ xt,
        float* __restrict__ xr)
{
    int r = blockIdx.x, tid = threadIdx.x;
    int beg = ptr[r], end = ptr[r+1];
    float M1 = m1[r], I1 = 1.f/(s1[r] + 1e-16f);
    float M2 = m2[r], I2 = 1.f/(s2[r] + 1e-16f);
    float acc = 0.f;
    bool act = tid < 100;
    for (int p = beg; p < end; ++p){
        int e = lst[p];
        int h = ei[e], t = ei[N_E + e];
        float a1 = expf(e1l[e] - M1)*I1;
        float a2 = expf(e2l[e] - M2)*I2;
        if (act) acc += a1*xh[(size_t)h*100 + tid] + a2*xt[(size_t)t*100 + tid];
    }
    if (act) xr[(size_t)r*100 + tid] = acc;
}

__global__ __launch_bounds__(128)
void k_gatr_agg(const int* __restrict__ ptr, const int* __restrict__ lst,
        const int* __restrict__ ei,
        const float* __restrict__ er, const float* __restrict__ mr, const float* __restrict__ sr,
        const float* __restrict__ xcur, float* __restrict__ xbig)
{
    int r = blockIdx.x, tid = threadIdx.x;
    int beg = ptr[r], end = ptr[r+1];
    float M = mr[r], I = 1.f/(sr[r] + 1e-16f);
    float a0 = 0.f, a1 = 0.f, a2 = 0.f;
    for (int p = beg; p < end; ++p){
        int e = lst[p];
        int t = ei[N_E + e];
        float a = expf(er[e] - M)*I;
        const float* xw = xcur + (size_t)t*D_EH;
        a0 += a*xw[tid];
        a1 += a*xw[tid+128];
        if (tid < 44) a2 += a*xw[tid+256];
    }
    float* orow = xbig + (size_t)r*D_X + 300;
    orow[tid]     = a0;
    orow[tid+128] = a1;
    if (tid < 44) orow[tid+256] = a2;
}

__global__ __launch_bounds__(128)
void k_gat_agg(const int* __restrict__ ptr, const int* __restrict__ col,
        const float* __restrict__ di, const float* __restrict__ dj,
        const float* __restrict__ mN, const float* __restrict__ sN,
        float* __restrict__ xbig)
{
    int n = blockIdx.x, tid = threadIdx.x;
    int beg = ptr[n], end = ptr[n+1];
    float M = mN[n], I = 1.f/(sN[n] + 1e-16f), dn = di[n];
    float a0 = 0.f, a1 = 0.f, a2 = 0.f;
    for (int p = beg; p < end; ++p){
        int j = col[p];
        float a = expf(lrelu_f(dn + dj[j]) - M)*I;
        const float* xw = xbig + (size_t)j*D_X;
        a0 += a*xw[tid];
        a1 += a*xw[tid+128];
        if (tid < 44) a2 += a*xw[tid+256];
    }
    float* orow = xbig + (size_t)n*D_X + 600;
    orow[tid]     = lrelu_f(a0);
    orow[tid+128] = lrelu_f(a1);
    if (tid < 44) orow[tid+256] = lrelu_f(a2);
}

// ---------------- misc elementwise ----------------
__global__ void k_copy300(const float* __restrict__ src, float* __restrict__ dst){
    int i = blockIdx.x*blockDim.x + threadIdx.x;
    if (i < N_NODES*D_EH){
        int n = i / D_EH, d = i - n*D_EH;
        dst[(size_t)n*D_X + d] = src[i];
    }
}

__global__ void k_scale9(const float* __restrict__ src, float* __restrict__ dst, int n){
    int i = blockIdx.x*blockDim.x + threadIdx.x;
    if (i < n) dst[i] = 9.f*src[i];
}

__global__ void k_lstm_cell(const float* __restrict__ gates, float* __restrict__ h,
        float* __restrict__ c, int H, float* __restrict__ outp, int slot){
    int i = blockIdx.x*blockDim.x + threadIdx.x;
    if (i < N_NODES*H){
        int n = i / H, cd = i - n*H;
        const float* g = gates + (size_t)n*4*H;
        float ig = sigm_f(g[cd]);
        float fg = sigm_f(g[H + cd]);
        float gg = tanhf(g[2*H + cd]);
        float og = sigm_f(g[3*H + cd]);
        float cn = fg*c[i] + ig*gg;
        float hn = og*tanhf(cn);
        c[i] = cn; h[i] = hn;
        outp[(size_t)n*D_X + slot + cd] = hn;
    }
}

// ---------------- attend ----------------
__global__ void k_gather(const float* __restrict__ src, const int* __restrict__ dbp,
                         float* __restrict__ dst){
    int b = blockIdx.x, tid = threadIdx.x;
    int idx = dbp[b*2];
    const float* s = src + (size_t)idx*D_X;
    float* d = dst + (size_t)b*D_X;
    for (int x = tid; x < D_X; x += 256) d[x] = s[x];
}

__global__ __launch_bounds__(256) void k_row_softmax(float* __restrict__ X, int ld, int cols){
    __shared__ float red[256];
    int r = blockIdx.x, tid = threadIdx.x;
    float* row = X + (size_t)r*ld;
    float mm = -3.4e38f;
    for (int c = tid; c < cols; c += 256) mm = fmaxf(mm, row[c]);
    red[tid] = mm; __syncthreads();
    for (int st = 128; st > 0; st >>= 1){ if (tid < st) red[tid] = fmaxf(red[tid], red[tid+st]); __syncthreads(); }
    float M = red[0]; __syncthreads();
    float ss = 0.f;
    for (int c = tid; c < cols; c += 256){ float e = expf(row[c] - M); row[c] = e; ss += e; }
    red[tid] = ss; __syncthreads();
    for (int st = 128; st > 0; st >>= 1){ if (tid < st) red[tid] += red[tid+st]; __syncthreads(); }
    float inv = 1.f/red[0];
    for (int c = tid; c < cols; c += 256) row[c] *= inv;
}

__global__ void k_re_init(const float* __restrict__ Xq, float* __restrict__ Re){
    int i = blockIdx.x*blockDim.x + threadIdx.x;
    if (i < 3*N_B*D_X){
        int k = i / (N_B*D_X);
        int rem = i - k*(N_B*D_X);
        int b = rem / D_X, d = rem - b*D_X;
        Re[((size_t)b*3 + k)*D_X + d] = Xq[i];
    }
}

__global__ __launch_bounds__(64) void k_mk_out(const float* __restrict__ hid,
        const float* __restrict__ w2, const float* __restrict__ b2,
        float* __restrict__ sc){
    int rowi = blockIdx.x, lane = threadIdx.x;
    const float* row = hid + (size_t)rowi*450;
    float s = 0.f;
    for (int d = lane; d < 450; d += 64) s += row[d]*w2[d];
    for (int off = 32; off > 0; off >>= 1) s += __shfl_xor(s, off);
    if (lane == 0) sc[rowi] = sigm_f(s + b2[0]);
}

__global__ void k_kg(const float* __restrict__ sc, float* __restrict__ kg){
    int b = blockIdx.x*blockDim.x + threadIdx.x;
    if (b < N_B){
        float a = sc[b*3], b1 = sc[b*3+1], c2 = sc[b*3+2];
        float m = fmaxf(a, fmaxf(b1, c2));
        float ea = expf(a-m), eb = expf(b1-m), ec = expf(c2-m);
        float inv = 1.f/(ea+eb+ec);
        kg[b*3] = ea*inv; kg[b*3+1] = eb*inv; kg[b*3+2] = ec*inv;
    }
}

__global__ void k_winner(const int* __restrict__ dbp, int* __restrict__ win){
    int b = blockIdx.x*blockDim.x + threadIdx.x;
    if (b < N_B) atomicMax(&win[dbp[b*2]], b);
}

__global__ __launch_bounds__(256) void k_out_softmax(const float* __restrict__ nbuf,
        const int* __restrict__ win, const float* __restrict__ kg, int col,
        float* __restrict__ out){
    __shared__ float red[256];
    int n = blockIdx.x, tid = threadIdx.x;
    int w = win[n];
    float s = (w >= 0) ? kg[w*3 + col] : 1.f;
    const float* row = nbuf + (size_t)n*D_X;
    float* orow = out + (size_t)n*D_X;
    float mm = -3.4e38f;
    for (int d = tid; d < D_X; d += 256) mm = fmaxf(mm, row[d]*s);
    red[tid] = mm; __syncthreads();
    for (int st = 128; st > 0; st >>= 1){ if (tid < st) red[tid] = fmaxf(red[tid], red[tid+st]); __syncthreads(); }
    float M = red[0]; __syncthreads();
    float ss = 0.f;
    for (int d = tid; d < D_X; d += 256){ float e = expf(row[d]*s - M); orow[d] = e; ss += e; }
    red[tid] = ss; __syncthreads();
    for (int st = 128; st > 0; st >>= 1){ if (tid < st) red[tid] += red[tid+st]; __syncthreads(); }
    float inv = 1.f/red[0];
    for (int d = tid; d < D_X; d += 256) orow[d] *= inv;
}

// ---------------- host ----------------
static void gemm_abt_l(hipStream_t st, const float* A, int lda, const float* B, int ldb,
                       float* C, int ldc, int M, int N, int K,
                       const float* b1, const float* b2, int accum, int act){
    dim3 g((N+63)/64, (M+63)/64);
    gemm_abt<<<g, dim3(256), 0, st>>>(A, lda, B, ldb, C, ldc, M, N, K, b1, b2, accum, act);
}

extern "C" void kernel_launch(void* const* d_in, const int* in_sizes, int n_in,
                              void* d_out, int out_size, void* d_ws, size_t ws_size,
                              hipStream_t stream)
{
    const float* x_e1   = (const float*)d_in[0];
    const int*   ei1    = (const int*)  d_in[1];
    const int*   rel1   = (const int*)  d_in[2];
    const int*   eia1   = (const int*)  d_in[3];
    const float* xname1 = (const float*)d_in[5];
    const float* oneh1  = (const float*)d_in[6];
    const float* x_e2   = (const float*)d_in[7];
    const int*   ei2    = (const int*)  d_in[8];
    const int*   rel2   = (const int*)  d_in[9];
    const int*   eia2   = (const int*)  d_in[10];
    const float* xname2 = (const float*)d_in[12];
    const float* oneh2  = (const float*)d_in[13];
    const int*   dbat   = (const int*)  d_in[14];
    const float* hw1_w  = (const float*)d_in[15];
    const float* hw2_w  = (const float*)d_in[16];
    const float* ge_wh  = (const float*)d_in[17];
    const float* ge_wt  = (const float*)d_in[18];
    const float* ge_ah1 = (const float*)d_in[19];
    const float* ge_ah2 = (const float*)d_in[20];
    const float* ge_at1 = (const float*)d_in[21];
    const float* ge_at2 = (const float*)d_in[22];
    const float* gr_ah  = (const float*)d_in[23];
    const float* gr_ar  = (const float*)d_in[24];
    const float* g_ai   = (const float*)d_in[25];
    const float* g_aj   = (const float*)d_in[26];
    const float* l1wif  = (const float*)d_in[27];
    const float* l1whf  = (const float*)d_in[28];
    const float* l1bif  = (const float*)d_in[29];
    const float* l1bhf  = (const float*)d_in[30];
    const float* l1wib  = (const float*)d_in[31];
    const float* l1whb  = (const float*)d_in[32];
    const float* l1bib  = (const float*)d_in[33];
    const float* l1bhb  = (const float*)d_in[34];
    const float* l2wi   = (const float*)d_in[35];
    const float* l2wh   = (const float*)d_in[36];
    const float* l2bi   = (const float*)d_in[37];
    const float* l2bh   = (const float*)d_in[38];
    const float* mk_w1  = (const float*)d_in[39];
    const float* mk_b1  = (const float*)d_in[40];
    const float* mk_w2  = (const float*)d_in[41];
    const float* mk_b2  = (const float*)d_in[42];

    float* out = (float*)d_out;
    const size_t CHK = (size_t)N_NODES*D_X;
    float* x1o = out;             float* n1 = out + CHK;     float* h1o = out + 2*CHK;
    float* x2o = out + 3*CHK;     float* n2 = out + 4*CHK;   float* h2o = out + 5*CHK;

    float* F = (float*)d_ws;
    size_t fo = 0;
    auto AL = [&](size_t n){ float* p = F + fo; fo += n; return p; };
    float* P0 = AL((size_t)N_NODES*D_X);      // xbig | gates(lo) | attend bufs
    float* P1 = AL((size_t)N_NODES*D_EH);     // xcur | gates(hi)
    float* P2 = AL((size_t)N_NODES*D_EH);     // gcn-out | h
    float* P3 = AL((size_t)N_NODES*D_EH);     // gate-tmp | c
    float* xh  = AL((size_t)N_NODES*100);
    float* xt  = AL((size_t)N_NODES*100);
    float* vh1 = AL(N_NODES); float* vh2 = AL(N_NODES);
    float* vt1 = AL(N_NODES); float* vt2 = AL(N_NODES);
    float* dis = AL(N_NODES);
    float* ehd = AL(N_NODES);
    float* dI  = AL(N_NODES); float* dJ = AL(N_NODES);
    float* mN  = AL(N_NODES); float* sN = AL(N_NODES);
    float* e1l = AL(N_E); float* e2l = AL(N_E); float* erl = AL(N_E);
    float* xr  = AL((size_t)N_R*100);
    float* m1 = AL(N_R); float* s1 = AL(N_R);
    float* m2 = AL(N_R); float* s2 = AL(N_R);
    float* mr = AL(N_R); float* sr = AL(N_R);
    float* sc  = AL(3*N_B);
    float* kg1 = AL(3*N_B);
    float* kg2 = AL(3*N_B);
    int* I = (int*)(F + fo);
    size_t io = 0;
    auto ALI = [&](size_t n){ int* p = I + io; io += n; return p; };
    int* degi   = ALI(N_NODES);
    int* rowptr = ALI(N_NODES+1);
    int* cursor = ALI(N_NODES);
    int* colsrc = ALI(N_EA);
    int* relcnt = ALI(N_R);
    int* relptr = ALI(N_R+1);
    int* relcur = ALI(N_R);
    int* reledge= ALI(N_E);
    int* win1   = ALI(N_NODES);
    int* win2   = ALI(N_NODES);
    size_t need = fo*sizeof(float) + io*sizeof(int);
    if (ws_size < need){
        fprintf(stderr, "DSEA kernel: ws too small (%zu < %zu)\n", ws_size, need);
        return;
    }

    // attend aliases inside P0 (free during attend phase)
    float* Sbuf = P0;                                  // 512*15000
    float* Xq   = Sbuf + (size_t)N_B*N_NODES;          // 3*512*900
    float* Re   = Xq + (size_t)3*N_B*D_X;              // 512*3*900
    float* hid  = Re + (size_t)3*N_B*D_X;              // 1536*450

    auto side = [&](const float* xe, const int* ei, const int* rel, const int* eia,
                    const float* xnm, const float* onh,
                    float* xo, float* nb, float* ob)
    {
        float* xbig = P0;
        float* xcur = P1;
        float* tA = P2;
        float* tB = P3;
        // ---- node CSR over ei_all (grouped by target i = row1, storing source j) ----
        hipMemsetAsync(degi, 0, N_NODES*sizeof(int), stream);
        k_count<<<dim3((N_EA+255)/256), dim3(256), 0, stream>>>(eia + N_EA, N_EA, degi);
        k_scan<<<dim3(1), dim3(1024), 0, stream>>>(degi, rowptr, N_NODES);
        hipMemsetAsync(cursor, 0, N_NODES*sizeof(int), stream);
        k_fill_node_csr<<<dim3((N_EA+255)/256), dim3(256), 0, stream>>>(eia, N_EA, rowptr, cursor, colsrc);
        k_dis<<<dim3((N_NODES+255)/256), dim3(256), 0, stream>>>(degi, dis, N_NODES);
        hipMemcpyAsync(xcur, xe, (size_t)N_NODES*D_EH*sizeof(float), hipMemcpyDeviceToDevice, stream);
        // ---- 2x highway(gcn) ----
        for (int hwi = 0; hwi < 2; ++hwi){
            const float* w = hwi ? hw2_w : hw1_w;
            k_gcn_agg<<<dim3(N_NODES), dim3(128), 0, stream>>>(xcur, rowptr, colsrc, dis, tA);
            gemm_abt_l(stream, xcur, D_EH, w, D_EH, tB, D_EH, N_NODES, D_EH, D_EH, nullptr, nullptr, 0, 3);
            k_highway<<<dim3((N_NODES*D_EH+255)/256), dim3(256), 0, stream>>>(xcur, tA, tB, N_NODES*D_EH);
        }
        // ---- rel CSR ----
        hipMemsetAsync(relcnt, 0, N_R*sizeof(int), stream);
        k_count<<<dim3((N_E+255)/256), dim3(256), 0, stream>>>(rel, N_E, relcnt);
        k_scan<<<dim3(1), dim3(1024), 0, stream>>>(relcnt, relptr, N_R);
        hipMemsetAsync(relcur, 0, N_R*sizeof(int), stream);
        k_fill_rel_csr<<<dim3((N_E+255)/256), dim3(256), 0, stream>>>(rel, N_E, relptr, relcur, reledge);
        // ---- gat_e ----
        gemm_abt_l(stream, xcur, D_EH, ge_wh, D_EH, xh, 100, N_NODES, 100, D_EH, nullptr, nullptr, 0, 0);
        gemm_abt_l(stream, xcur, D_EH, ge_wt, D_EH, xt, 100, N_NODES, 100, D_EH, nullptr, nullptr, 0, 0);
        k_rowdot2<<<dim3(N_NODES), dim3(256), 0, stream>>>(xh, 100, 100, ge_ah1, ge_at1, vh1, vh2);
        k_rowdot2<<<dim3(N_NODES), dim3(256), 0, stream>>>(xt, 100, 100, ge_ah2, ge_at2, vt1, vt2);
        k_edge_gate<<<dim3((N_E+255)/256), dim3(256), 0, stream>>>(ei, vh1, vt1, vh2, vt2, e1l, e2l);
        k_seg_ms<<<dim3(N_R), dim3(256), 0, stream>>>(relptr, reledge, e1l, e2l, m1, s1, m2, s2);
        k_gate_agg<<<dim3(N_R), dim3(128), 0, stream>>>(relptr, reledge, ei, e1l, m1, s1, e2l, m2, s2, xh, xt, xr);
        // ---- gat_r ----
        k_rowdot2<<<dim3(N_NODES), dim3(256), 0, stream>>>(xcur, D_EH, D_EH, gr_ah, (const float*)nullptr, ehd, (float*)nullptr);
        k_rowdot2<<<dim3(N_R), dim3(256), 0, stream>>>(xr, 100, 100, gr_ar, (const float*)nullptr, vh1, (float*)nullptr);
        k_edge_gatr<<<dim3((N_E+255)/256), dim3(256), 0, stream>>>(ei, rel, ehd, vh1, erl);
        k_seg_ms<<<dim3(N_R), dim3(256), 0, stream>>>(relptr, reledge, erl, (const float*)nullptr, mr, sr, (float*)nullptr, (float*)nullptr);
        hipMemsetAsync(xbig, 0, (size_t)N_NODES*D_X*sizeof(float), stream);
        k_copy300<<<dim3((N_NODES*D_EH+255)/256), dim3(256), 0, stream>>>(xcur, xbig);
        k_gatr_agg<<<dim3(N_R), dim3(128), 0, stream>>>(relptr, reledge, ei, erl, mr, sr, xcur, xbig);
        // ---- gat (over ei_all, on 600-dim concat) ----
        k_rowdot2<<<dim3(N_NODES), dim3(256), 0, stream>>>(xbig, D_X, 600, g_ai, g_aj, dI, dJ);
        k_seg_ms_node<<<dim3(N_NODES), dim3(64), 0, stream>>>(rowptr, colsrc, dI, dJ, mN, sN);
        k_gat_agg<<<dim3(N_NODES), dim3(128), 0, stream>>>(rowptr, colsrc, dI, dJ, mN, sN, xbig);
        k_scale9<<<dim3((unsigned)((CHK+255)/256)), dim3(256), 0, stream>>>(xbig, xo, (int)CHK);
        // ---- LSTMs (gates overlays P0+P1; h=P2, c=P3) ----
        float* gates = P0;
        float* hb = P2;
        float* cb = P3;
        // l1 forward (H=150)
        hipMemsetAsync(hb, 0, (size_t)N_NODES*150*sizeof(float), stream);
        hipMemsetAsync(cb, 0, (size_t)N_NODES*150*sizeof(float), stream);
        for (int t = 0; t < 3; ++t){
            gemm_abt_l(stream, xnm + t*300, D_X, l1wif, 300, gates, 600, N_NODES, 600, 300, l1bif, l1bhf, 0, 0);
            if (t) gemm_abt_l(stream, hb, 150, l1whf, 150, gates, 600, N_NODES, 600, 150, nullptr, nullptr, 1, 0);
            k_lstm_cell<<<dim3((N_NODES*150+255)/256), dim3(256), 0, stream>>>(gates, hb, cb, 150, nb, t*300);
        }
        // l1 backward
        hipMemsetAsync(hb, 0, (size_t)N_NODES*150*sizeof(float), stream);
        hipMemsetAsync(cb, 0, (size_t)N_NODES*150*sizeof(float), stream);
        for (int tp = 0; tp < 3; ++tp){
            int tin = 2 - tp;
            gemm_abt_l(stream, xnm + tin*300, D_X, l1wib, 300, gates, 600, N_NODES, 600, 300, l1bib, l1bhb, 0, 0);
            if (tp) gemm_abt_l(stream, hb, 150, l1whb, 150, gates, 600, N_NODES, 600, 150, nullptr, nullptr, 1, 0);
            k_lstm_cell<<<dim3((N_NODES*150+255)/256), dim3(256), 0, stream>>>(gates, hb, cb, 150, nb, tin*300 + 150);
        }
        // l2 (H=300)
        hipMemsetAsync(hb, 0, (size_t)N_NODES*300*sizeof(float), stream);
        hipMemsetAsync(cb, 0, (size_t)N_NODES*300*sizeof(float), stream);
        for (int t = 0; t < 3; ++t){
            gemm_abt_l(stream, onh + t*300, D_X, l2wi, 300, gates, 1200, N_NODES, 1200, 300, l2bi, l2bh, 0, 0);
            if (t) gemm_abt_l(stream, hb, 300, l2wh, 300, gates, 1200, N_NODES, 1200, 300, nullptr, nullptr, 1, 0);
            k_lstm_cell<<<dim3((N_NODES*300+255)/256), dim3(256), 0, stream>>>(gates, hb, cb, 300, ob, t*300);
        }
    };

    auto attend = [&](const float* xa, const float* na, const float* oa,
                      const float* xb, const float* nb, const float* ob,
                      const int* dbp, float* kg)
    {
        const float* qs[3] = {xa, na, oa};
        const float* ks[3] = {xb, nb, ob};
        for (int k = 0; k < 3; ++k)
            k_gather<<<dim3(N_B), dim3(256), 0, stream>>>(qs[k], dbp, Xq + (size_t)k*N_B*D_X);
        k_re_init<<<dim3((3*N_B*D_X+255)/256), dim3(256), 0, stream>>>(Xq, Re);
        for (int k = 0; k < 3; ++k){
            gemm_abt_l(stream, Xq + (size_t)k*N_B*D_X, D_X, ks[k], D_X, Sbuf, N_NODES, N_B, N_NODES, D_X, nullptr, nullptr, 0, 0);
            k_row_softmax<<<dim3(N_B), dim3(256), 0, stream>>>(Sbuf, N_NODES, N_NODES);
            int kc = ((N_NODES + 8*16 - 1)/(8*16))*16;   // 1888
            dim3 g((D_X+63)/64, (N_B+63)/64, 8);
            gemm_ab_splitk<<<g, dim3(256), 0, stream>>>(Sbuf, N_NODES, ks[k], D_X, Re + (size_t)k*D_X, 3*D_X, N_B, D_X, N_NODES, kc);
        }
        // mk over all (b,k) rows at once: Re viewed as (1536,900)
        gemm_abt_l(stream, Re, D_X, mk_w1, D_X, hid, 450, 3*N_B, 450, D_X, mk_b1, nullptr, 0, 2);
        k_mk_out<<<dim3(3*N_B), dim3(64), 0, stream>>>(hid, mk_w2, mk_b2, sc);
        k_kg<<<dim3((N_B+255)/256), dim3(256), 0, stream>>>(sc, kg);
    };

    side(x_e1, ei1, rel1, eia1, xname1, oneh1, x1o, n1, h1o);
    side(x_e2, ei2, rel2, eia2, xname2, oneh2, x2o, n2, h2o);

    hipMemsetAsync(win1, 0xFF, N_NODES*sizeof(int), stream);
    hipMemsetAsync(win2, 0xFF, N_NODES*sizeof(int), stream);
    k_winner<<<dim3((N_B+255)/256), dim3(256), 0, stream>>>(dbat, win1);
    k_winner<<<dim3((N_B+255)/256), dim3(256), 0, stream>>>(dbat + 1, win2);

    attend(x1o, n1, h1o, x2o, n2, h2o, dbat, kg1);
    attend(x2o, n2, h2o, x1o, n1, h1o, dbat + 1, kg2);

    // final softmaxes (in place on d_out chunks)
    k_out_softmax<<<dim3(N_NODES), dim3(256), 0, stream>>>(n1, win1, kg1, 1, n1);
    k_out_softmax<<<dim3(N_NODES), dim3(256), 0, stream>>>(h1o, win1, kg1, 2, h1o);
    k_out_softmax<<<dim3(N_NODES), dim3(256), 0, stream>>>(n2, win2, kg2, 1, n2);
    k_out_softmax<<<dim3(N_NODES), dim3(256), 0, stream>>>(h2o, win2, kg2, 2, h2o);
}

// Round 2
// 10488.673 us; speedup vs baseline: 1.4010x; 1.4010x over previous
//
#include <hip/hip_runtime.h>
#include <cstdio>

#define N_NODES 15000
#define N_E     200000
#define N_EA    400000
#define N_R     1000
#define N_B     512
#define D_EH    300
#define D_X     900

typedef __attribute__((ext_vector_type(8))) short bf16x8;
typedef __attribute__((ext_vector_type(4))) float f32x4;

__device__ __forceinline__ float lrelu_f(float x){ return x > 0.f ? x : 0.01f*x; }
__device__ __forceinline__ float sigm_f(float x){ return 1.f/(1.f+expf(-x)); }
__device__ __forceinline__ short f2b(float f){
    union { float f; unsigned u; } x; x.f = f;
    unsigned u = x.u;
    u += 0x7fff + ((u >> 16) & 1);   // RTNE
    return (short)(u >> 16);
}

// ---------------- CSR build ----------------
__global__ void k_count(const int* __restrict__ tgt, int n, int* __restrict__ cnt){
    int i = blockIdx.x*blockDim.x + threadIdx.x;
    if (i < n) atomicAdd(&cnt[tgt[i]], 1);
}

__global__ __launch_bounds__(1024) void k_scan(const int* __restrict__ cnt, int* __restrict__ ptr, int n){
    __shared__ int part[1024];
    int tid = threadIdx.x;
    int chunk = (n + 1023) >> 10;
    int beg = tid*chunk, end = min(n, beg+chunk);
    int s = 0;
    for (int i = beg; i < end; ++i) s += cnt[i];
    part[tid] = s;
    __syncthreads();
    if (tid == 0){
        int run = 0;
        for (int i = 0; i < 1024; ++i){ int v = part[i]; part[i] = run; run += v; }
        ptr[n] = run;
    }
    __syncthreads();
    int run = part[tid];
    for (int i = beg; i < end; ++i){ ptr[i] = run; run += cnt[i]; }
}

__global__ void k_fill_node_csr(const int* __restrict__ ei, int n, const int* __restrict__ ptr,
                                int* __restrict__ cur, int* __restrict__ col){
    int e = blockIdx.x*blockDim.x + threadIdx.x;
    if (e < n){
        int j = ei[e], i = ei[n + e];
        int p = atomicAdd(&cur[i], 1);
        col[ptr[i] + p] = j;
    }
}

__global__ void k_fill_rel_csr(const int* __restrict__ rel, int n, const int* __restrict__ ptr,
                               int* __restrict__ cur, int* __restrict__ out){
    int e = blockIdx.x*blockDim.x + threadIdx.x;
    if (e < n){
        int r = rel[e];
        int p = atomicAdd(&cur[r], 1);
        out[ptr[r] + p] = e;
    }
}

__global__ void k_dis(const int* __restrict__ cnt, float* __restrict__ dis, int n){
    int i = blockIdx.x*blockDim.x + threadIdx.x;
    if (i < n){ int d = cnt[i]; dis[i] = d > 0 ? rsqrtf((float)d) : 0.f; }
}

// ---------------- GCN ----------------
__global__ __launch_bounds__(128) void k_gcn_agg(const float* __restrict__ x,
        const int* __restrict__ ptr, const int* __restrict__ col,
        const float* __restrict__ dis, float* __restrict__ out){
    int n = blockIdx.x, tid = threadIdx.x;
    int beg = ptr[n], end = ptr[n+1];
    float a0 = 0.f, a1 = 0.f, a2 = 0.f;
    for (int p = beg; p < end; ++p){
        int j = col[p];
        float dj = dis[j];
        const float* xr = x + (size_t)j*D_EH;
        a0 += dj * xr[tid];
        a1 += dj * xr[tid+128];
        if (tid < 44) a2 += dj * xr[tid+256];
    }
    float dn = dis[n];
    float* orow = out + (size_t)n*D_EH;
    orow[tid]     = fmaxf(dn*a0, 0.f);
    orow[tid+128] = fmaxf(dn*a1, 0.f);
    if (tid < 44) orow[tid+256] = fmaxf(dn*a2, 0.f);
}

__global__ void k_highway(float* __restrict__ x1, const float* __restrict__ x2,
                          const float* __restrict__ g, int n){
    int i = blockIdx.x*blockDim.x + threadIdx.x;
    if (i < n){
        float gg = g[i];
        x1[i] = lrelu_f(gg*x2[i] + (1.f-gg)*x1[i]);
    }
}

// ---------------- MFMA bf16 GEMM ----------------
// C(M,N) = act( [C +] A(M,K) @ op(B) + bias1 + bias2 ), fp32 in/out,
// bf16 conversion during LDS staging. btrans=0: B is (N,K) row-major (A@B^T form);
// btrans=1: B is (K,N) row-major (A@B form, transposed into LDS).
// grid.z split-K with kc chunk (multiple of 32); atomic=1 -> atomicAdd epilogue.
#define BM 128
#define BN 128
#define BK 32
#define LDT 40

__global__ __launch_bounds__(256)
void mfma_gemm(const float* __restrict__ A, int lda,
               const float* __restrict__ B, int ldb,
               float* __restrict__ C, int ldc,
               int M, int N, int K, int kc,
               const float* __restrict__ bias1, const float* __restrict__ bias2,
               int accum, int act, int atomic, int btrans)
{
    __shared__ short As[BM*LDT];
    __shared__ short Bs[BN*LDT];
    const int tid = threadIdx.x;
    const int bm = blockIdx.y*BM, bn = blockIdx.x*BN;
    const int kbeg = blockIdx.z*kc;
    const int kend = min(K, kbeg + kc);
    const int wave = tid >> 6, lane = tid & 63;
    const int wr = (wave >> 1)*64, wc = (wave & 1)*64;
    const int lr = lane & 15, lq = lane >> 4;

    f32x4 acc[4][4];
    #pragma unroll
    for (int i = 0; i < 4; ++i)
        #pragma unroll
        for (int j = 0; j < 4; ++j)
            acc[i][j] = (f32x4){0.f, 0.f, 0.f, 0.f};

    for (int k0 = kbeg; k0 < kend; k0 += BK){
        // ---- stage A: BM x BK (float2 granularity, 2048 f2, 8/thread) ----
        #pragma unroll
        for (int p = 0; p < 8; ++p){
            int idx = p*256 + tid;
            int row = idx >> 4;          // BK/2 = 16 f2 per row
            int c2  = idx & 15;
            int gm = bm + row, gk = k0 + c2*2;
            float vx = 0.f, vy = 0.f;
            if (gm < M){
                const float* ap = A + (size_t)gm*lda + gk;
                if (gk + 1 < kend){ float2 v = *(const float2*)ap; vx = v.x; vy = v.y; }
                else if (gk < kend){ vx = ap[0]; }
            }
            short2* dst = (short2*)&As[row*LDT + c2*2];
            *dst = make_short2(f2b(vx), f2b(vy));
        }
        // ---- stage B ----
        if (!btrans){
            #pragma unroll
            for (int p = 0; p < 8; ++p){
                int idx = p*256 + tid;
                int row = idx >> 4;
                int c2  = idx & 15;
                int gn = bn + row, gk = k0 + c2*2;
                float vx = 0.f, vy = 0.f;
                if (gn < N){
                    const float* bp = B + (size_t)gn*ldb + gk;
                    if (gk + 1 < kend){ float2 v = *(const float2*)bp; vx = v.x; vy = v.y; }
                    else if (gk < kend){ vx = bp[0]; }
                }
                short2* dst = (short2*)&Bs[row*LDT + c2*2];
                *dst = make_short2(f2b(vx), f2b(vy));
            }
        } else {
            #pragma unroll
            for (int p = 0; p < 8; ++p){
                int idx = p*256 + tid;
                int kr = idx >> 6;          // 0..31
                int c2 = idx & 63;          // n-group
                int gk = k0 + kr, gn = bn + c2*2;
                float vx = 0.f, vy = 0.f;
                if (gk < kend){
                    const float* bp = B + (size_t)gk*ldb + gn;
                    if (gn + 1 < N){ float2 v = *(const float2*)bp; vx = v.x; vy = v.y; }
                    else if (gn < N){ vx = bp[0]; }
                }
                Bs[(c2*2  )*LDT + kr] = f2b(vx);
                Bs[(c2*2+1)*LDT + kr] = f2b(vy);
            }
        }
        __syncthreads();

        bf16x8 af[4], bf[4];
        #pragma unroll
        for (int i = 0; i < 4; ++i)
            af[i] = *(const bf16x8*)&As[(wr + i*16 + lr)*LDT + lq*8];
        #pragma unroll
        for (int j = 0; j < 4; ++j)
            bf[j] = *(const bf16x8*)&Bs[(wc + j*16 + lr)*LDT + lq*8];
        #pragma unroll
        for (int i = 0; i < 4; ++i)
            #pragma unroll
            for (int j = 0; j < 4; ++j)
                acc[i][j] = __builtin_amdgcn_mfma_f32_16x16x32_bf16(af[i], bf[j], acc[i][j], 0, 0, 0);
        __syncthreads();
    }

    // ---- epilogue: C/D layout col=lane&15, row=lq*4+reg ----
    #pragma unroll
    for (int i = 0; i < 4; ++i){
        int mb = bm + wr + i*16 + lq*4;
        #pragma unroll
        for (int r = 0; r < 4; ++r){
            int m = mb + r;
            if (m >= M) continue;
            float* Crow = C + (size_t)m*ldc;
            #pragma unroll
            for (int j = 0; j < 4; ++j){
                int n = bn + wc + j*16 + lr;
                if (n >= N) continue;
                float v = acc[i][j][r];
                if (atomic){
                    atomicAdd(&Crow[n], v);
                } else {
                    if (bias1) v += bias1[n];
                    if (bias2) v += bias2[n];
                    if (accum) v += Crow[n];
                    if (act == 1) v = lrelu_f(v);
                    else if (act == 2) v = fmaxf(v, 0.f);
                    else if (act == 3) v = lrelu_f(v + 1e-8f);
                    Crow[n] = v;
                }
            }
        }
    }
}

// ---------------- fp32 GEMM (kept for small precision-sensitive gemms) ----------------
__global__ __launch_bounds__(256)
void gemm_abt(const float* __restrict__ A, int lda,
              const float* __restrict__ B, int ldb,
              float* __restrict__ C, int ldc,
              int M, int N, int K,
              const float* __restrict__ bias1,
              const float* __restrict__ bias2,
              int accum, int act)
{
    __shared__ float As[16][65];
    __shared__ float Bs[16][65];
    const int bm = blockIdx.y*64, bn = blockIdx.x*64;
    const int tid = threadIdx.x;
    const int tx = tid & 15, ty = tid >> 4;
    const int ar = tid >> 2, ac = (tid & 3) << 2;
    float acc[4][4] = {{0.f}};
    for (int k0 = 0; k0 < K; k0 += 16){
        int am = bm + ar;
        const float* Arow = A + (size_t)am*lda;
        #pragma unroll
        for (int u = 0; u < 4; ++u){
            int kk = ac + u, k = k0 + kk;
            As[kk][ar] = (am < M && k < K) ? Arow[k] : 0.f;
        }
        int bnr = bn + ar;
        const float* Brow = B + (size_t)bnr*ldb;
        #pragma unroll
        for (int u = 0; u < 4; ++u){
            int kk = ac + u, k = k0 + kk;
            Bs[kk][ar] = (bnr < N && k < K) ? Brow[k] : 0.f;
        }
        __syncthreads();
        #pragma unroll
        for (int kk = 0; kk < 16; ++kk){
            float a[4], b[4];
            #pragma unroll
            for (int i = 0; i < 4; ++i) a[i] = As[kk][(ty<<2)+i];
            #pragma unroll
            for (int j = 0; j < 4; ++j) b[j] = Bs[kk][(tx<<2)+j];
            #pragma unroll
            for (int i = 0; i < 4; ++i)
                #pragma unroll
                for (int j = 0; j < 4; ++j)
                    acc[i][j] = fmaf(a[i], b[j], acc[i][j]);
        }
        __syncthreads();
    }
    #pragma unroll
    for (int i = 0; i < 4; ++i){
        int m = bm + (ty<<2) + i;
        if (m >= M) continue;
        float* Crow = C + (size_t)m*ldc;
        #pragma unroll
        for (int j = 0; j < 4; ++j){
            int n = bn + (tx<<2) + j;
            if (n >= N) continue;
            float v = acc[i][j];
            if (bias1) v += bias1[n];
            if (bias2) v += bias2[n];
            if (accum) v += Crow[n];
            if (act == 1) v = lrelu_f(v);
            else if (act == 2) v = fmaxf(v, 0.f);
            else if (act == 3) v = lrelu_f(v + 1e-8f);
            Crow[n] = v;
        }
    }
}

// ---------------- row dots / edge values ----------------
__global__ __launch_bounds__(256) void k_rowdot2(const float* __restrict__ X, int ldx, int D,
        const float* __restrict__ v1, const float* __restrict__ v2,
        float* __restrict__ o1, float* __restrict__ o2){
    __shared__ float s1s[256], s2s[256];
    int n = blockIdx.x, tid = threadIdx.x;
    const float* row = X + (size_t)n*ldx;
    float s1 = 0.f, s2 = 0.f;
    for (int d = tid; d < D; d += 256){
        float x = row[d];
        s1 += x*v1[d];
        if (v2) s2 += x*v2[d];
    }
    s1s[tid] = s1; s2s[tid] = s2;
    __syncthreads();
    for (int st = 128; st > 0; st >>= 1){
        if (tid < st){ s1s[tid] += s1s[tid+st]; s2s[tid] += s2s[tid+st]; }
        __syncthreads();
    }
    if (tid == 0){ o1[n] = s1s[0]; if (o2) o2[n] = s2s[0]; }
}

__global__ void k_edge_gate(const int* __restrict__ ei,
        const float* __restrict__ vh1, const float* __restrict__ vt1,
        const float* __restrict__ vh2, const float* __restrict__ vt2,
        float* __restrict__ e1l, float* __restrict__ e2l){
    int e = blockIdx.x*blockDim.x + threadIdx.x;
    if (e < N_E){
        int h = ei[e], t = ei[N_E + e];
        e1l[e] = lrelu_f(vh1[h] + vt1[t]);
        e2l[e] = lrelu_f(vh2[h] + vt2[t]);
    }
}

__global__ void k_edge_gatr(const int* __restrict__ ei, const int* __restrict__ rel,
        const float* __restrict__ ehd, const float* __restrict__ rdot,
        float* __restrict__ er){
    int e = blockIdx.x*blockDim.x + threadIdx.x;
    if (e < N_E){
        int h = ei[e];
        er[e] = lrelu_f(ehd[h] + rdot[rel[e]]);
    }
}

// ---------------- segment softmax stats ----------------
__global__ __launch_bounds__(256)
void k_seg_ms(const int* __restrict__ ptr, const int* __restrict__ lst,
              const float* __restrict__ v1, const float* __restrict__ v2,
              float* __restrict__ m1, float* __restrict__ s1,
              float* __restrict__ m2, float* __restrict__ s2)
{
    __shared__ float r1[256], r2[256];
    const int r = blockIdx.x, tid = threadIdx.x;
    const int beg = ptr[r], end = ptr[r+1];
    float mm1 = -3.4e38f, mm2 = -3.4e38f;
    for (int p = beg + tid; p < end; p += 256){
        int e = lst[p];
        mm1 = fmaxf(mm1, v1[e]);
        if (v2) mm2 = fmaxf(mm2, v2[e]);
    }
    r1[tid] = mm1; r2[tid] = mm2;
    __syncthreads();
    for (int st = 128; st > 0; st >>= 1){
        if (tid < st){ r1[tid] = fmaxf(r1[tid], r1[tid+st]); r2[tid] = fmaxf(r2[tid], r2[tid+st]); }
        __syncthreads();
    }
    float M1 = r1[0], M2 = r2[0];
    __syncthreads();
    float ss1 = 0.f, ss2 = 0.f;
    for (int p = beg + tid; p < end; p += 256){
        int e = lst[p];
        ss1 += expf(v1[e] - M1);
        if (v2) ss2 += expf(v2[e] - M2);
    }
    r1[tid] = ss1; r2[tid] = ss2;
    __syncthreads();
    for (int st = 128; st > 0; st >>= 1){
        if (tid < st){ r1[tid] += r1[tid+st]; r2[tid] += r2[tid+st]; }
        __syncthreads();
    }
    if (tid == 0){
        m1[r] = M1; s1[r] = r1[0];
        if (m2){ m2[r] = M2; s2[r] = r2[0]; }
    }
}

__global__ __launch_bounds__(64)
void k_seg_ms_node(const int* __restrict__ ptr, const int* __restrict__ col,
                   const float* __restrict__ di, const float* __restrict__ dj,
                   float* __restrict__ mN, float* __restrict__ sN)
{
    const int n = blockIdx.x, lane = threadIdx.x;
    const int beg = ptr[n], end = ptr[n+1];
    const float dn = di[n];
    float mm = -3.4e38f;
    for (int p = beg + lane; p < end; p += 64)
        mm = fmaxf(mm, lrelu_f(dn + dj[col[p]]));
    for (int off = 32; off > 0; off >>= 1)
        mm = fmaxf(mm, __shfl_xor(mm, off));
    float ss = 0.f;
    for (int p = beg + lane; p < end; p += 64)
        ss += expf(lrelu_f(dn + dj[col[p]]) - mm);
    for (int off = 32; off > 0; off >>= 1)
        ss += __shfl_xor(ss, off);
    if (lane == 0){ mN[n] = mm; sN[n] = ss; }
}

// ---------------- segment aggregations ----------------
__global__ __launch_bounds__(128)
void k_gate_agg(const int* __restrict__ ptr, const int* __restrict__ lst,
        const int* __restrict__ ei,
        const float* __restrict__ e1l, const float* __restrict__ m1, const float* __restrict__ s1,
        const float* __restrict__ e2l, const float* __restrict__ m2, const float* __restrict__ s2,
        const float* __restrict__ xh, const float* __restrict__ xt,
        float* __restrict__ xr)
{
    int r = blockIdx.x, tid = threadIdx.x;
    int beg = ptr[r], end = ptr[r+1];
    float M1 = m1[r], I1 = 1.f/(s1[r] + 1e-16f);
    float M2 = m2[r], I2 = 1.f/(s2[r] + 1e-16f);
    float acc = 0.f;
    bool act = tid < 100;
    for (int p = beg; p < end; ++p){
        int e = lst[p];
        int h = ei[e], t = ei[N_E + e];
        float a1 = expf(e1l[e] - M1)*I1;
        float a2 = expf(e2l[e] - M2)*I2;
        if (act) acc += a1*xh[(size_t)h*100 + tid] + a2*xt[(size_t)t*100 + tid];
    }
    if (act) xr[(size_t)r*100 + tid] = acc;
}

__global__ __launch_bounds__(128)
void k_gatr_agg(const int* __restrict__ ptr, const int* __restrict__ lst,
        const int* __restrict__ ei,
        const float* __restrict__ er, const float* __restrict__ mr, const float* __restrict__ sr,
        const float* __restrict__ xcur, float* __restrict__ xbig)
{
    int r = blockIdx.x, tid = threadIdx.x;
    int beg = ptr[r], end = ptr[r+1];
    float M = mr[r], I = 1.f/(sr[r] + 1e-16f);
    float a0 = 0.f, a1 = 0.f, a2 = 0.f;
    for (int p = beg; p < end; ++p){
        int e = lst[p];
        int t = ei[N_E + e];
        float a = expf(er[e] - M)*I;
        const float* xw = xcur + (size_t)t*D_EH;
        a0 += a*xw[tid];
        a1 += a*xw[tid+128];
        if (tid < 44) a2 += a*xw[tid+256];
    }
    float* orow = xbig + (size_t)r*D_X + 300;
    orow[tid]     = a0;
    orow[tid+128] = a1;
    if (tid < 44) orow[tid+256] = a2;
}

__global__ __launch_bounds__(128)
void k_gat_agg(const int* __restrict__ ptr, const int* __restrict__ col,
        const float* __restrict__ di, const float* __restrict__ dj,
        const float* __restrict__ mN, const float* __restrict__ sN,
        float* __restrict__ xbig)
{
    int n = blockIdx.x, tid = threadIdx.x;
    int beg = ptr[n], end = ptr[n+1];
    float M = mN[n], I = 1.f/(sN[n] + 1e-16f), dn = di[n];
    float a0 = 0.f, a1 = 0.f, a2 = 0.f;
    for (int p = beg; p < end; ++p){
        int j = col[p];
        float a = expf(lrelu_f(dn + dj[j]) - M)*I;
        const float* xw = xbig + (size_t)j*D_X;
        a0 += a*xw[tid];
        a1 += a*xw[tid+128];
        if (tid < 44) a2 += a*xw[tid+256];
    }
    float* orow = xbig + (size_t)n*D_X + 600;
    orow[tid]     = lrelu_f(a0);
    orow[tid+128] = lrelu_f(a1);
    if (tid < 44) orow[tid+256] = lrelu_f(a2);
}

// ---------------- misc elementwise ----------------
__global__ void k_copy300(const float* __restrict__ src, float* __restrict__ dst){
    int i = blockIdx.x*blockDim.x + threadIdx.x;
    if (i < N_NODES*D_EH){
        int n = i / D_EH, d = i - n*D_EH;
        dst[(size_t)n*D_X + d] = src[i];
    }
}

__global__ void k_scale9(const float* __restrict__ src, float* __restrict__ dst, int n){
    int i = blockIdx.x*blockDim.x + threadIdx.x;
    if (i < n) dst[i] = 9.f*src[i];
}

__global__ void k_lstm_cell(const float* __restrict__ gates, float* __restrict__ h,
        float* __restrict__ c, int H, float* __restrict__ outp, int slot){
    int i = blockIdx.x*blockDim.x + threadIdx.x;
    if (i < N_NODES*H){
        int n = i / H, cd = i - n*H;
        const float* g = gates + (size_t)n*4*H;
        float ig = sigm_f(g[cd]);
        float fg = sigm_f(g[H + cd]);
        float gg = tanhf(g[2*H + cd]);
        float og = sigm_f(g[3*H + cd]);
        float cn = fg*c[i] + ig*gg;
        float hn = og*tanhf(cn);
        c[i] = cn; h[i] = hn;
        outp[(size_t)n*D_X + slot + cd] = hn;
    }
}

// ---------------- attend ----------------
__global__ void k_gather(const float* __restrict__ src, const int* __restrict__ dbp,
                         float* __restrict__ dst){
    int b = blockIdx.x, tid = threadIdx.x;
    int idx = dbp[b*2];
    const float* s = src + (size_t)idx*D_X;
    float* d = dst + (size_t)b*D_X;
    for (int x = tid; x < D_X; x += 256) d[x] = s[x];
}

__global__ __launch_bounds__(256) void k_row_softmax(float* __restrict__ X, int ld, int cols){
    __shared__ float red[256];
    int r = blockIdx.x, tid = threadIdx.x;
    float* row = X + (size_t)r*ld;
    float mm = -3.4e38f;
    for (int c = tid; c < cols; c += 256) mm = fmaxf(mm, row[c]);
    red[tid] = mm; __syncthreads();
    for (int st = 128; st > 0; st >>= 1){ if (tid < st) red[tid] = fmaxf(red[tid], red[tid+st]); __syncthreads(); }
    float M = red[0]; __syncthreads();
    float ss = 0.f;
    for (int c = tid; c < cols; c += 256){ float e = expf(row[c] - M); row[c] = e; ss += e; }
    red[tid] = ss; __syncthreads();
    for (int st = 128; st > 0; st >>= 1){ if (tid < st) red[tid] += red[tid+st]; __syncthreads(); }
    float inv = 1.f/red[0];
    for (int c = tid; c < cols; c += 256) row[c] *= inv;
}

__global__ void k_re_init(const float* __restrict__ Xq, float* __restrict__ Re){
    int i = blockIdx.x*blockDim.x + threadIdx.x;
    if (i < 3*N_B*D_X){
        int k = i / (N_B*D_X);
        int rem = i - k*(N_B*D_X);
        int b = rem / D_X, d = rem - b*D_X;
        Re[((size_t)b*3 + k)*D_X + d] = Xq[i];
    }
}

__global__ __launch_bounds__(64) void k_mk_out(const float* __restrict__ hid,
        const float* __restrict__ w2, const float* __restrict__ b2,
        float* __restrict__ sc){
    int rowi = blockIdx.x, lane = threadIdx.x;
    const float* row = hid + (size_t)rowi*450;
    float s = 0.f;
    for (int d = lane; d < 450; d += 64) s += row[d]*w2[d];
    for (int off = 32; off > 0; off >>= 1) s += __shfl_xor(s, off);
    if (lane == 0) sc[rowi] = sigm_f(s + b2[0]);
}

__global__ void k_kg(const float* __restrict__ sc, float* __restrict__ kg){
    int b = blockIdx.x*blockDim.x + threadIdx.x;
    if (b < N_B){
        float a = sc[b*3], b1 = sc[b*3+1], c2 = sc[b*3+2];
        float m = fmaxf(a, fmaxf(b1, c2));
        float ea = expf(a-m), eb = expf(b1-m), ec = expf(c2-m);
        float inv = 1.f/(ea+eb+ec);
        kg[b*3] = ea*inv; kg[b*3+1] = eb*inv; kg[b*3+2] = ec*inv;
    }
}

__global__ void k_winner(const int* __restrict__ dbp, int* __restrict__ win){
    int b = blockIdx.x*blockDim.x + threadIdx.x;
    if (b < N_B) atomicMax(&win[dbp[b*2]], b);
}

__global__ __launch_bounds__(256) void k_out_softmax(const float* __restrict__ nbuf,
        const int* __restrict__ win, const float* __restrict__ kg, int col,
        float* __restrict__ out){
    __shared__ float red[256];
    int n = blockIdx.x, tid = threadIdx.x;
    int w = win[n];
    float s = (w >= 0) ? kg[w*3 + col] : 1.f;
    const float* row = nbuf + (size_t)n*D_X;
    float* orow = out + (size_t)n*D_X;
    float mm = -3.4e38f;
    for (int d = tid; d < D_X; d += 256) mm = fmaxf(mm, row[d]*s);
    red[tid] = mm; __syncthreads();
    for (int st = 128; st > 0; st >>= 1){ if (tid < st) red[tid] = fmaxf(red[tid], red[tid+st]); __syncthreads(); }
    float M = red[0]; __syncthreads();
    float ss = 0.f;
    for (int d = tid; d < D_X; d += 256){ float e = expf(row[d]*s - M); orow[d] = e; ss += e; }
    red[tid] = ss; __syncthreads();
    for (int st = 128; st > 0; st >>= 1){ if (tid < st) red[tid] += red[tid+st]; __syncthreads(); }
    float inv = 1.f/red[0];
    for (int d = tid; d < D_X; d += 256) orow[d] *= inv;
}

// ---------------- host ----------------
static void gemm_abt_l(hipStream_t st, const float* A, int lda, const float* B, int ldb,
                       float* C, int ldc, int M, int N, int K,
                       const float* b1, const float* b2, int accum, int act){
    dim3 g((N+63)/64, (M+63)/64);
    gemm_abt<<<g, dim3(256), 0, st>>>(A, lda, B, ldb, C, ldc, M, N, K, b1, b2, accum, act);
}

static void mgemm(hipStream_t st, const float* A, int lda, const float* B, int ldb,
                  float* C, int ldc, int M, int N, int K,
                  const float* b1, const float* b2, int accum, int act){
    dim3 g((N+127)/128, (M+127)/128, 1);
    mfma_gemm<<<g, dim3(256), 0, st>>>(A, lda, B, ldb, C, ldc, M, N, K, K, b1, b2, accum, act, 0, 0);
}

extern "C" void kernel_launch(void* const* d_in, const int* in_sizes, int n_in,
                              void* d_out, int out_size, void* d_ws, size_t ws_size,
                              hipStream_t stream)
{
    const float* x_e1   = (const float*)d_in[0];
    const int*   ei1    = (const int*)  d_in[1];
    const int*   rel1   = (const int*)  d_in[2];
    const int*   eia1   = (const int*)  d_in[3];
    const float* xname1 = (const float*)d_in[5];
    const float* oneh1  = (const float*)d_in[6];
    const float* x_e2   = (const float*)d_in[7];
    const int*   ei2    = (const int*)  d_in[8];
    const int*   rel2   = (const int*)  d_in[9];
    const int*   eia2   = (const int*)  d_in[10];
    const float* xname2 = (const float*)d_in[12];
    const float* oneh2  = (const float*)d_in[13];
    const int*   dbat   = (const int*)  d_in[14];
    const float* hw1_w  = (const float*)d_in[15];
    const float* hw2_w  = (const float*)d_in[16];
    const float* ge_wh  = (const float*)d_in[17];
    const float* ge_wt  = (const float*)d_in[18];
    const float* ge_ah1 = (const float*)d_in[19];
    const float* ge_ah2 = (const float*)d_in[20];
    const float* ge_at1 = (const float*)d_in[21];
    const float* ge_at2 = (const float*)d_in[22];
    const float* gr_ah  = (const float*)d_in[23];
    const float* gr_ar  = (const float*)d_in[24];
    const float* g_ai   = (const float*)d_in[25];
    const float* g_aj   = (const float*)d_in[26];
    const float* l1wif  = (const float*)d_in[27];
    const float* l1whf  = (const float*)d_in[28];
    const float* l1bif  = (const float*)d_in[29];
    const float* l1bhf  = (const float*)d_in[30];
    const float* l1wib  = (const float*)d_in[31];
    const float* l1whb  = (const float*)d_in[32];
    const float* l1bib  = (const float*)d_in[33];
    const float* l1bhb  = (const float*)d_in[34];
    const float* l2wi   = (const float*)d_in[35];
    const float* l2wh   = (const float*)d_in[36];
    const float* l2bi   = (const float*)d_in[37];
    const float* l2bh   = (const float*)d_in[38];
    const float* mk_w1  = (const float*)d_in[39];
    const float* mk_b1  = (const float*)d_in[40];
    const float* mk_w2  = (const float*)d_in[41];
    const float* mk_b2  = (const float*)d_in[42];

    float* out = (float*)d_out;
    const size_t CHK = (size_t)N_NODES*D_X;
    float* x1o = out;             float* n1 = out + CHK;     float* h1o = out + 2*CHK;
    float* x2o = out + 3*CHK;     float* n2 = out + 4*CHK;   float* h2o = out + 5*CHK;

    float* F = (float*)d_ws;
    size_t fo = 0;
    auto AL = [&](size_t n){ float* p = F + fo; fo += n; return p; };
    float* P0 = AL((size_t)N_NODES*D_X);      // xbig | gates(lo) | attend bufs
    float* P1 = AL((size_t)N_NODES*D_EH);     // xcur | gates(hi)
    float* P2 = AL((size_t)N_NODES*D_EH);     // gcn-out | h
    float* P3 = AL((size_t)N_NODES*D_EH);     // gate-tmp | c
    float* xh  = AL((size_t)N_NODES*100);
    float* xt  = AL((size_t)N_NODES*100);
    float* vh1 = AL(N_NODES); float* vh2 = AL(N_NODES);
    float* vt1 = AL(N_NODES); float* vt2 = AL(N_NODES);
    float* dis = AL(N_NODES);
    float* ehd = AL(N_NODES);
    float* dI  = AL(N_NODES); float* dJ = AL(N_NODES);
    float* mN  = AL(N_NODES); float* sN = AL(N_NODES);
    float* e1l = AL(N_E); float* e2l = AL(N_E); float* erl = AL(N_E);
    float* xr  = AL((size_t)N_R*100);
    float* m1 = AL(N_R); float* s1 = AL(N_R);
    float* m2 = AL(N_R); float* s2 = AL(N_R);
    float* mr = AL(N_R); float* sr = AL(N_R);
    float* sc  = AL(3*N_B);
    float* kg1 = AL(3*N_B);
    float* kg2 = AL(3*N_B);
    int* I = (int*)(F + fo);
    size_t io = 0;
    auto ALI = [&](size_t n){ int* p = I + io; io += n; return p; };
    int* degi   = ALI(N_NODES);
    int* rowptr = ALI(N_NODES+1);
    int* cursor = ALI(N_NODES);
    int* colsrc = ALI(N_EA);
    int* relcnt = ALI(N_R);
    int* relptr = ALI(N_R+1);
    int* relcur = ALI(N_R);
    int* reledge= ALI(N_E);
    int* win1   = ALI(N_NODES);
    int* win2   = ALI(N_NODES);
    size_t need = fo*sizeof(float) + io*sizeof(int);
    if (ws_size < need){
        fprintf(stderr, "DSEA kernel: ws too small (%zu < %zu)\n", ws_size, need);
        return;
    }

    // attend aliases inside P0 (free during attend phase)
    float* Sbuf = P0;                                  // 512*15000
    float* Xq   = Sbuf + (size_t)N_B*N_NODES;          // 3*512*900
    float* Re   = Xq + (size_t)3*N_B*D_X;              // 512*3*900
    float* hid  = Re + (size_t)3*N_B*D_X;              // 1536*450

    auto side = [&](const float* xe, const int* ei, const int* rel, const int* eia,
                    const float* xnm, const float* onh,
                    float* xo, float* nb, float* ob)
    {
        float* xbig = P0;
        float* xcur = P1;
        float* tA = P2;
        float* tB = P3;
        // ---- node CSR over ei_all ----
        hipMemsetAsync(degi, 0, N_NODES*sizeof(int), stream);
        k_count<<<dim3((N_EA+255)/256), dim3(256), 0, stream>>>(eia + N_EA, N_EA, degi);
        k_scan<<<dim3(1), dim3(1024), 0, stream>>>(degi, rowptr, N_NODES);
        hipMemsetAsync(cursor, 0, N_NODES*sizeof(int), stream);
        k_fill_node_csr<<<dim3((N_EA+255)/256), dim3(256), 0, stream>>>(eia, N_EA, rowptr, cursor, colsrc);
        k_dis<<<dim3((N_NODES+255)/256), dim3(256), 0, stream>>>(degi, dis, N_NODES);
        hipMemcpyAsync(xcur, xe, (size_t)N_NODES*D_EH*sizeof(float), hipMemcpyDeviceToDevice, stream);
        // ---- 2x highway(gcn) : gate gemm now MFMA bf16 ----
        for (int hwi = 0; hwi < 2; ++hwi){
            const float* w = hwi ? hw2_w : hw1_w;
            k_gcn_agg<<<dim3(N_NODES), dim3(128), 0, stream>>>(xcur, rowptr, colsrc, dis, tA);
            mgemm(stream, xcur, D_EH, w, D_EH, tB, D_EH, N_NODES, D_EH, D_EH, nullptr, nullptr, 0, 3);
            k_highway<<<dim3((N_NODES*D_EH+255)/256), dim3(256), 0, stream>>>(xcur, tA, tB, N_NODES*D_EH);
        }
        // ---- rel CSR ----
        hipMemsetAsync(relcnt, 0, N_R*sizeof(int), stream);
        k_count<<<dim3((N_E+255)/256), dim3(256), 0, stream>>>(rel, N_E, relcnt);
        k_scan<<<dim3(1), dim3(1024), 0, stream>>>(relcnt, relptr, N_R);
        hipMemsetAsync(relcur, 0, N_R*sizeof(int), stream);
        k_fill_rel_csr<<<dim3((N_E+255)/256), dim3(256), 0, stream>>>(rel, N_E, relptr, relcur, reledge);
        // ---- gat_e (small gemms stay fp32) ----
        gemm_abt_l(stream, xcur, D_EH, ge_wh, D_EH, xh, 100, N_NODES, 100, D_EH, nullptr, nullptr, 0, 0);
        gemm_abt_l(stream, xcur, D_EH, ge_wt, D_EH, xt, 100, N_NODES, 100, D_EH, nullptr, nullptr, 0, 0);
        k_rowdot2<<<dim3(N_NODES), dim3(256), 0, stream>>>(xh, 100, 100, ge_ah1, ge_at1, vh1, vh2);
        k_rowdot2<<<dim3(N_NODES), dim3(256), 0, stream>>>(xt, 100, 100, ge_ah2, ge_at2, vt1, vt2);
        k_edge_gate<<<dim3((N_E+255)/256), dim3(256), 0, stream>>>(ei, vh1, vt1, vh2, vt2, e1l, e2l);
        k_seg_ms<<<dim3(N_R), dim3(256), 0, stream>>>(relptr, reledge, e1l, e2l, m1, s1, m2, s2);
        k_gate_agg<<<dim3(N_R), dim3(128), 0, stream>>>(relptr, reledge, ei, e1l, m1, s1, e2l, m2, s2, xh, xt, xr);
        // ---- gat_r ----
        k_rowdot2<<<dim3(N_NODES), dim3(256), 0, stream>>>(xcur, D_EH, D_EH, gr_ah, (const float*)nullptr, ehd, (float*)nullptr);
        k_rowdot2<<<dim3(N_R), dim3(256), 0, stream>>>(xr, 100, 100, gr_ar, (const float*)nullptr, vh1, (float*)nullptr);
        k_edge_gatr<<<dim3((N_E+255)/256), dim3(256), 0, stream>>>(ei, rel, ehd, vh1, erl);
        k_seg_ms<<<dim3(N_R), dim3(256), 0, stream>>>(relptr, reledge, erl, (const float*)nullptr, mr, sr, (float*)nullptr, (float*)nullptr);
        hipMemsetAsync(xbig, 0, (size_t)N_NODES*D_X*sizeof(float), stream);
        k_copy300<<<dim3((N_NODES*D_EH+255)/256), dim3(256), 0, stream>>>(xcur, xbig);
        k_gatr_agg<<<dim3(N_R), dim3(128), 0, stream>>>(relptr, reledge, ei, erl, mr, sr, xcur, xbig);
        // ---- gat (over ei_all, on 600-dim concat) ----
        k_rowdot2<<<dim3(N_NODES), dim3(256), 0, stream>>>(xbig, D_X, 600, g_ai, g_aj, dI, dJ);
        k_seg_ms_node<<<dim3(N_NODES), dim3(64), 0, stream>>>(rowptr, colsrc, dI, dJ, mN, sN);
        k_gat_agg<<<dim3(N_NODES), dim3(128), 0, stream>>>(rowptr, colsrc, dI, dJ, mN, sN, xbig);
        k_scale9<<<dim3((unsigned)((CHK+255)/256)), dim3(256), 0, stream>>>(xbig, xo, (int)CHK);
        // ---- LSTMs (gates overlays P0+P1; h=P2, c=P3), all gemms MFMA bf16 ----
        float* gates = P0;
        float* hb = P2;
        float* cb = P3;
        // l1 forward (H=150)
        hipMemsetAsync(hb, 0, (size_t)N_NODES*150*sizeof(float), stream);
        hipMemsetAsync(cb, 0, (size_t)N_NODES*150*sizeof(float), stream);
        for (int t = 0; t < 3; ++t){
            mgemm(stream, xnm + t*300, D_X, l1wif, 300, gates, 600, N_NODES, 600, 300, l1bif, l1bhf, 0, 0);
            if (t) mgemm(stream, hb, 150, l1whf, 150, gates, 600, N_NODES, 600, 150, nullptr, nullptr, 1, 0);
            k_lstm_cell<<<dim3((N_NODES*150+255)/256), dim3(256), 0, stream>>>(gates, hb, cb, 150, nb, t*300);
        }
        // l1 backward
        hipMemsetAsync(hb, 0, (size_t)N_NODES*150*sizeof(float), stream);
        hipMemsetAsync(cb, 0, (size_t)N_NODES*150*sizeof(float), stream);
        for (int tp = 0; tp < 3; ++tp){
            int tin = 2 - tp;
            mgemm(stream, xnm + tin*300, D_X, l1wib, 300, gates, 600, N_NODES, 600, 300, l1bib, l1bhb, 0, 0);
            if (tp) mgemm(stream, hb, 150, l1whb, 150, gates, 600, N_NODES, 600, 150, nullptr, nullptr, 1, 0);
            k_lstm_cell<<<dim3((N_NODES*150+255)/256), dim3(256), 0, stream>>>(gates, hb, cb, 150, nb, tin*300 + 150);
        }
        // l2 (H=300)
        hipMemsetAsync(hb, 0, (size_t)N_NODES*300*sizeof(float), stream);
        hipMemsetAsync(cb, 0, (size_t)N_NODES*300*sizeof(float), stream);
        for (int t = 0; t < 3; ++t){
            mgemm(stream, onh + t*300, D_X, l2wi, 300, gates, 1200, N_NODES, 1200, 300, l2bi, l2bh, 0, 0);
            if (t) mgemm(stream, hb, 300, l2wh, 300, gates, 1200, N_NODES, 1200, 300, nullptr, nullptr, 1, 0);
            k_lstm_cell<<<dim3((N_NODES*300+255)/256), dim3(256), 0, stream>>>(gates, hb, cb, 300, ob, t*300);
        }
    };

    auto attend = [&](const float* xa, const float* na, const float* oa,
                      const float* xb, const float* nb, const float* ob,
                      const int* dbp, float* kg)
    {
        const float* qs[3] = {xa, na, oa};
        const float* ks[3] = {xb, nb, ob};
        for (int k = 0; k < 3; ++k)
            k_gather<<<dim3(N_B), dim3(256), 0, stream>>>(qs[k], dbp, Xq + (size_t)k*N_B*D_X);
        k_re_init<<<dim3((3*N_B*D_X+255)/256), dim3(256), 0, stream>>>(Xq, Re);
        for (int k = 0; k < 3; ++k){
            // S = Xq @ Xk^T  (MFMA bf16)
            mgemm(stream, Xq + (size_t)k*N_B*D_X, D_X, ks[k], D_X, Sbuf, N_NODES, N_B, N_NODES, D_X, nullptr, nullptr, 0, 0);
            k_row_softmax<<<dim3(N_B), dim3(256), 0, stream>>>(Sbuf, N_NODES, N_NODES);
            // Re += softmax(S) @ Xk  (MFMA bf16, btrans staging, 8-way split-K, atomic)
            const int Z = 8;
            int kc = ((N_NODES + Z*32 - 1)/(Z*32))*32;   // 1888
            dim3 g((D_X+127)/128, (N_B+127)/128, Z);
            mfma_gemm<<<g, dim3(256), 0, stream>>>(Sbuf, N_NODES, ks[k], D_X, Re + (size_t)k*D_X, 3*D_X,
                                                   N_B, D_X, N_NODES, kc, nullptr, nullptr, 0, 0, 1, 1);
        }
        // mk hidden over all (b,k) rows: Re viewed as (1536,900)
        mgemm(stream, Re, D_X, mk_w1, D_X, hid, 450, 3*N_B, 450, D_X, mk_b1, nullptr, 0, 2);
        k_mk_out<<<dim3(3*N_B), dim3(64), 0, stream>>>(hid, mk_w2, mk_b2, sc);
        k_kg<<<dim3((N_B+255)/256), dim3(256), 0, stream>>>(sc, kg);
    };

    side(x_e1, ei1, rel1, eia1, xname1, oneh1, x1o, n1, h1o);
    side(x_e2, ei2, rel2, eia2, xname2, oneh2, x2o, n2, h2o);

    hipMemsetAsync(win1, 0xFF, N_NODES*sizeof(int), stream);
    hipMemsetAsync(win2, 0xFF, N_NODES*sizeof(int), stream);
    k_winner<<<dim3((N_B+255)/256), dim3(256), 0, stream>>>(dbat, win1);
    k_winner<<<dim3((N_B+255)/256), dim3(256), 0, stream>>>(dbat + 1, win2);

    attend(x1o, n1, h1o, x2o, n2, h2o, dbat, kg1);
    attend(x2o, n2, h2o, x1o, n1, h1o, dbat + 1, kg2);

    // final softmaxes (in place on d_out chunks)
    k_out_softmax<<<dim3(N_NODES), dim3(256), 0, stream>>>(n1, win1, kg1, 1, n1);
    k_out_softmax<<<dim3(N_NODES), dim3(256), 0, stream>>>(h1o, win1, kg1, 2, h1o);
    k_out_softmax<<<dim3(N_NODES), dim3(256), 0, stream>>>(n2, win2, kg2, 1, n2);
    k_out_softmax<<<dim3(N_NODES), dim3(256), 0, stream>>>(h2o, win2, kg2, 2, h2o);
}